// Round 2
// baseline (240.506 us; speedup 1.0000x reference)
//
#include <hip/hip_runtime.h>
#include <hip/hip_bf16.h>
#include <math.h>

#define DTC 0.01f

typedef __attribute__((ext_vector_type(8))) short short8;   // 8 x bf16 (4 VGPRs)
typedef __attribute__((ext_vector_type(4))) float f32x4;    // MFMA C/D
typedef unsigned short bf16raw;

__device__ __forceinline__ bf16raw f2bf(float f){
  union { unsigned u; float f; } v; v.f = f;
  unsigned r = v.u + 0x7FFF + ((v.u >> 16) & 1u);   // round-to-nearest-even
  return (bf16raw)(r >> 16);
}

// Load 8 consecutive fp32, round to 8 bf16.
__device__ __forceinline__ short8 ld8f(const float* __restrict__ p){
  float4 a = *(const float4*)p;
  float4 b = *(const float4*)(p + 4);
  short8 r;
  r[0] = (short)f2bf(a.x); r[1] = (short)f2bf(a.y);
  r[2] = (short)f2bf(a.z); r[3] = (short)f2bf(a.w);
  r[4] = (short)f2bf(b.x); r[5] = (short)f2bf(b.y);
  r[6] = (short)f2bf(b.z); r[7] = (short)f2bf(b.w);
  return r;
}

// ---------------------------------------------------------------------------
// Async-stage ITERS*16 rows x 32 bf16 (k-contiguous) -> LDS [row][32].
// Per instr: 64 lanes x 16B = 16 rows. LDS dest = wave-uniform base +
// lane*16B (HW scatter) — lane i covers row r0 + i/4, k-chunk (i%4)*8.
// ---------------------------------------------------------------------------
template<int ITERS>
__device__ __forceinline__ void stage_async(const bf16raw* __restrict__ src, long ld,
                                            long row0, int k0, bf16raw* lds,
                                            int wave, int lane){
#pragma unroll
  for (int i = 0; i < ITERS; ++i){
    int r0 = (wave*ITERS + i) * 16;
    long row = row0 + r0 + (lane >> 2);
    const bf16raw* gp = src + row*ld + k0 + (lane & 3)*8;
    bf16raw* lp = lds + r0*32;
    __builtin_amdgcn_global_load_lds((const __attribute__((address_space(1))) void*)gp,
                                     (__attribute__((address_space(3))) void*)lp,
                                     16, 0, 0);
  }
}

// One BK=32 step: 4 A-frags + NI B-frags (ds_read_b128) + 4*NI MFMA.
template<int NI>
__device__ __forceinline__ void mma_tile(const bf16raw* Alds, const bf16raw* Blds,
                                         f32x4 acc[4][NI], int wm, int wn, int quad, int t16){
  short8 af[4], bfr[NI];
#pragma unroll
  for (int mi = 0; mi < 4; ++mi)
    af[mi] = *(const short8*)(Alds + (wm*64 + mi*16 + t16)*32 + quad*8);
#pragma unroll
  for (int ni = 0; ni < NI; ++ni)
    bfr[ni] = *(const short8*)(Blds + (wn*(NI*16) + ni*16 + t16)*32 + quad*8);
#pragma unroll
  for (int mi = 0; mi < 4; ++mi)
#pragma unroll
    for (int ni = 0; ni < NI; ++ni)
      acc[mi][ni] = __builtin_amdgcn_mfma_f32_16x16x32_bf16(af[mi], bfr[ni], acc[mi][ni], 0, 0, 0);
}

// ---------------------------------------------------------------------------
// Prep: fp32 -> bf16 for u, [W_omega|W_zeta|W_B] (concat), C, D_mat.
// ---------------------------------------------------------------------------
extern "C" __global__ void k_prep(const float* __restrict__ u,
    const float* __restrict__ Wom, const float* __restrict__ Wze,
    const float* __restrict__ WB, const float* __restrict__ Cm,
    const float* __restrict__ Dm, bf16raw* __restrict__ u_bf,
    bf16raw* __restrict__ Wcat, bf16raw* __restrict__ C_bf,
    bf16raw* __restrict__ Dm_bf){
  long g = (long)blockIdx.x * 256 + threadIdx.x;
  const float* src; bf16raw* dst; long o;
  if      (g < 2097152){ src = u;   dst = u_bf;          o = g; }
  else if (g < 2105344){ src = Wom; dst = Wcat;          o = g - 2097152; }
  else if (g < 2113536){ src = Wze; dst = Wcat + 65536;  o = g - 2105344; }
  else if (g < 2129920){ src = WB;  dst = Wcat + 131072; o = g - 2113536; }
  else if (g < 2146304){ src = Cm;  dst = C_bf;          o = g - 2129920; }
  else                 { src = Dm;  dst = Dm_bf;         o = g - 2146304; }
  *(short8*)(dst + o*8) = ld8f(src + o*8);
}

// ---------------------------------------------------------------------------
// K1: P[bt][n] = sum_d u[bt][d] * Wcat[n][d]  (16384 x 256, K=1024), fp32 out.
// 2-phase double-buffered (stage next || MFMA cur), XCD-swizzled grid.
// ---------------------------------------------------------------------------
extern "C" __global__ __launch_bounds__(256) void k_gemm_p(
    const bf16raw* __restrict__ u_bf, const bf16raw* __restrict__ Wcat,
    float* __restrict__ P){
  __shared__ __align__(16) bf16raw Alds[2][128*32];
  __shared__ __align__(16) bf16raw Blds[2][128*32];
  int tid = threadIdx.x, wave = tid >> 6, lane = tid & 63;
  int quad = lane >> 4, t16 = lane & 15;
  int wm = wave >> 1, wn = wave & 1;
  // XCD-aware swizzle: 256 blocks, 8 XCDs x 32 consecutive blocks each.
  int id  = blockIdx.y * gridDim.x + blockIdx.x;
  int sid = (id & 7) * 32 + (id >> 3);
  long row0 = (long)(sid >> 1) * 128;
  int  col0 = (sid & 1) * 128;
  f32x4 acc[4][4] = {};

  stage_async<2>(u_bf, 1024, row0, 0, Alds[0], wave, lane);
  stage_async<2>(Wcat, 1024, col0, 0, Blds[0], wave, lane);
  asm volatile("s_waitcnt vmcnt(0)" ::: "memory");
  __builtin_amdgcn_s_barrier();
  __builtin_amdgcn_sched_barrier(0);
  int cur = 0;
  for (int kt = 0; kt < 31; ++kt){
    stage_async<2>(u_bf, 1024, row0, (kt+1)*32, Alds[cur^1], wave, lane);
    stage_async<2>(Wcat, 1024, col0, (kt+1)*32, Blds[cur^1], wave, lane);
    __builtin_amdgcn_s_setprio(1);
    mma_tile<4>(Alds[cur], Blds[cur], acc, wm, wn, quad, t16);
    __builtin_amdgcn_s_setprio(0);
    asm volatile("s_waitcnt vmcnt(0)" ::: "memory");
    __builtin_amdgcn_s_barrier();
    __builtin_amdgcn_sched_barrier(0);
    cur ^= 1;
  }
  mma_tile<4>(Alds[cur], Blds[cur], acc, wm, wn, quad, t16);
#pragma unroll
  for (int mi = 0; mi < 4; ++mi)
#pragma unroll
    for (int ni = 0; ni < 4; ++ni)
#pragma unroll
      for (int r = 0; r < 4; ++r){
        long grow = row0 + wm*64 + mi*16 + quad*4 + r;
        int  gcol = col0 + wn*64 + ni*16 + t16;
        P[grow*256 + gcol] = acc[mi][ni][r];
      }
}

// ---------------------------------------------------------------------------
// K4: out[bt][d] = sum_n Xs[bt][n]*C[d][n] + sum_e u[bt][e]*Dm[d][e], fp32 out.
// Unified 36-step K-loop (4 steps Xs@C^T + 32 steps u@Dm^T), 2-phase dbuf,
// XCD-swizzled grid (4 col-tiles of a row-panel land on one XCD's L2).
// ---------------------------------------------------------------------------
extern "C" __global__ __launch_bounds__(256, 2) void k_gemm_out(
    const bf16raw* __restrict__ Xs, const bf16raw* __restrict__ u_bf,
    const bf16raw* __restrict__ C_bf, const bf16raw* __restrict__ Dm_bf,
    float* __restrict__ out){
  __shared__ __align__(16) bf16raw Alds[2][128*32];
  __shared__ __align__(16) bf16raw Blds[2][256*32];
  int tid = threadIdx.x, wave = tid >> 6, lane = tid & 63;
  int quad = lane >> 4, t16 = lane & 15;
  int wm = wave >> 1, wn = wave & 1;
  // XCD-aware swizzle: 512 blocks, 8 XCDs x 64 consecutive blocks each.
  int id  = blockIdx.y * gridDim.x + blockIdx.x;
  int sid = (id & 7) * 64 + (id >> 3);
  long row0 = (long)(sid >> 2) * 128;
  int  col0 = (sid & 3) * 256;
  f32x4 acc[4][8] = {};

  auto stage = [&](int s, int buf){
    if (s < 4){
      stage_async<2>(Xs,   128, row0, s*32, Alds[buf], wave, lane);
      stage_async<4>(C_bf, 128, col0, s*32, Blds[buf], wave, lane);
    } else {
      stage_async<2>(u_bf,  1024, row0, (s-4)*32, Alds[buf], wave, lane);
      stage_async<4>(Dm_bf, 1024, col0, (s-4)*32, Blds[buf], wave, lane);
    }
  };

  stage(0, 0);
  asm volatile("s_waitcnt vmcnt(0)" ::: "memory");
  __builtin_amdgcn_s_barrier();
  __builtin_amdgcn_sched_barrier(0);
  int cur = 0;
  for (int s = 0; s < 35; ++s){
    stage(s+1, cur^1);
    __builtin_amdgcn_s_setprio(1);
    mma_tile<8>(Alds[cur], Blds[cur], acc, wm, wn, quad, t16);
    __builtin_amdgcn_s_setprio(0);
    asm volatile("s_waitcnt vmcnt(0)" ::: "memory");
    __builtin_amdgcn_s_barrier();
    __builtin_amdgcn_sched_barrier(0);
    cur ^= 1;
  }
  mma_tile<8>(Alds[cur], Blds[cur], acc, wm, wn, quad, t16);
#pragma unroll
  for (int mi = 0; mi < 4; ++mi)
#pragma unroll
    for (int ni = 0; ni < 8; ++ni)
#pragma unroll
      for (int r = 0; r < 4; ++r){
        long grow = row0 + wm*64 + mi*16 + quad*4 + r;
        int  gcol = col0 + wn*128 + ni*16 + t16;
        out[grow*1024 + gcol] = acc[mi][ni][r];
      }
}

// ---------------------------------------------------------------------------
// scanA: fused coef + chunk summary. 256 chunks x 16 steps; block = chunk;
// thread tid = (b,m) series. Reads P once, writes Coef + per-chunk 2x2
// transition matrix CM and offset vector CV.
// ---------------------------------------------------------------------------
extern "C" __global__ __launch_bounds__(256) void k_scanA(
    const float* __restrict__ P, const float* __restrict__ b_om,
    const float* __restrict__ b_ze, const float* __restrict__ b_B,
    float4* __restrict__ Coef, float4* __restrict__ CM, float2* __restrict__ CV){
  int tid = threadIdx.x, c = blockIdx.x;
  int b = tid >> 6, m = tid & 63;
  float bo = b_om[m], bz = b_ze[m], bb0 = b_B[m], bb1 = b_B[64 + m];
  const float* row = P + ((size_t)b*4096 + c*16) * 256;
  float4* cf = Coef + ((size_t)b*4096 + c*16) * 64 + m;
  float m00=1.f, m01=0.f, m10=0.f, m11=0.f, vz=0.f, vy=0.f;
#pragma unroll 4
  for (int t = 0; t < 16; ++t){
    const float* r = row + t*256;
    float wo = r[m]       + bo;
    float wz = r[64 + m]  + bz;
    float fz = r[128 + m] + bb0;
    float fy = r[192 + m] + bb1;
    float sp = (wo > 20.f) ? wo : log1pf(expf(wo));
    float omega = fminf(fmaxf(sp, 1e-4f), 100.f);
    float A = omega * omega;
    float S = 1.f / (1.f + DTC*DTC*A);
    float zeta = 1.f / (1.f + expf(-wz));
    float p = (1.f - zeta) * S;
    float q = p * DTC * A;
    cf[t*64] = make_float4(p, q, fz, fy);
    float nvz = p*vz - q*vy + fz;
    float nvy = DTC*p*vz + p*vy + fy;
    vz = nvz; vy = nvy;
    float n00 = p*m00 - q*m10;
    float n01 = p*m01 - q*m11;
    float n10 = DTC*p*m00 + p*m10;
    float n11 = DTC*p*m01 + p*m11;
    m00=n00; m01=n01; m10=n10; m11=n11;
  }
  CM[c*256 + tid] = make_float4(m00, m01, m10, m11);
  CV[c*256 + tid] = make_float2(vz, vy);
}

// ---------------------------------------------------------------------------
// scanC: block c composes its own exclusive chunk prefix from CM/CV
// (parallel across blocks — replaces the serial 1-block scan2), then applies
// its chunk from Coef, writing Xs (bf16). Xs overlays P — safe: P was fully
// consumed by k_scanA (prior kernel); scanC reads only Coef/CM/CV.
// ---------------------------------------------------------------------------
extern "C" __global__ __launch_bounds__(256) void k_scanC(
    const float4* __restrict__ Coef, const float4* __restrict__ CM,
    const float2* __restrict__ CV, bf16raw* __restrict__ Xs){
  int tid = threadIdx.x, c = blockIdx.x;
  int b = tid >> 6, m = tid & 63;
  float xz = 0.f, xy = 0.f;
#pragma unroll 4
  for (int j = 0; j < c; ++j){
    float4 Mv = CM[j*256 + tid];
    float2 Vv = CV[j*256 + tid];
    float nz = Mv.x*xz + Mv.y*xy + Vv.x;
    float ny = Mv.z*xz + Mv.w*xy + Vv.y;
    xz = nz; xy = ny;
  }
  const float4* cf = Coef + ((size_t)b*4096 + c*16) * 64 + m;
  bf16raw* xp = Xs + ((size_t)b*4096 + c*16) * 128 + m;
#pragma unroll 4
  for (int t = 0; t < 16; ++t){
    float4 f = cf[t*64];
    float nz = f.x*xz - f.y*xy + f.z;
    float ny = DTC*f.x*xz + f.x*xy + f.w;
    xz = nz; xy = ny;
    xp[t*128]      = f2bf(xz);   // z part: n = m
    xp[t*128 + 64] = f2bf(xy);   // y part: n = 64 + m
  }
}

// ---------------------------------------------------------------------------
extern "C" void kernel_launch(void* const* d_in, const int* in_sizes, int n_in,
                              void* d_out, int out_size, void* d_ws, size_t ws_size,
                              hipStream_t stream){
  const float* u   = (const float*)d_in[0];
  const float* Wom = (const float*)d_in[1];
  const float* bom = (const float*)d_in[2];
  const float* Wze = (const float*)d_in[3];
  const float* bze = (const float*)d_in[4];
  const float* WB  = (const float*)d_in[5];
  const float* bB  = (const float*)d_in[6];
  const float* Cm  = (const float*)d_in[7];
  const float* Dm  = (const float*)d_in[8];
  float* out = (float*)d_out;

  char* ws = (char*)d_ws;
  size_t off = 0;
  bf16raw* u_bf  = (bf16raw*)(ws + off); off += (size_t)16777216*2;    // 32 MB
  bf16raw* Wcat  = (bf16raw*)(ws + off); off += (size_t)262144*2;      // 512 KB
  bf16raw* C_bf  = (bf16raw*)(ws + off); off += (size_t)131072*2;      // 256 KB
  bf16raw* Dm_bf = (bf16raw*)(ws + off); off += (size_t)1048576*2;     // 2 MB
  float*   P     = (float*)  (ws + off);
  bf16raw* Xs    = (bf16raw*)P;          // overlay: P dead after k_scanA
  off += (size_t)16384*256*4;                                          // 16 MB
  float4*  Coef  = (float4*) (ws + off); off += (size_t)16384*64*16;   // 16 MB
  float4*  CMw   = (float4*) (ws + off); off += (size_t)256*256*16;    // 1 MB
  float2*  CVw   = (float2*) (ws + off); off += (size_t)256*256*8;     // 512 KB

  k_prep    <<<8896, 256, 0, stream>>>(u, Wom, Wze, WB, Cm, Dm, u_bf, Wcat, C_bf, Dm_bf);
  k_gemm_p  <<<dim3(2, 128), 256, 0, stream>>>(u_bf, Wcat, P);
  k_scanA   <<<256, 256, 0, stream>>>(P, bom, bze, bB, Coef, CMw, CVw);
  k_scanC   <<<256, 256, 0, stream>>>(Coef, CMw, CVw, Xs);
  k_gemm_out<<<dim3(4, 128), 256, 0, stream>>>(Xs, u_bf, C_bf, Dm_bf, out);
}

// Round 3
// 236.517 us; speedup vs baseline: 1.0169x; 1.0169x over previous
//
#include <hip/hip_runtime.h>
#include <hip/hip_bf16.h>
#include <math.h>

#define DTC 0.01f

typedef __attribute__((ext_vector_type(8))) short short8;   // 8 x bf16 (4 VGPRs)
typedef __attribute__((ext_vector_type(4))) float f32x4;    // MFMA C/D
typedef unsigned short bf16raw;

__device__ __forceinline__ bf16raw f2bf(float f){
  union { unsigned u; float f; } v; v.f = f;
  unsigned r = v.u + 0x7FFF + ((v.u >> 16) & 1u);   // round-to-nearest-even
  return (bf16raw)(r >> 16);
}

// Load 8 consecutive fp32, round to 8 bf16.
__device__ __forceinline__ short8 ld8f(const float* __restrict__ p){
  float4 a = *(const float4*)p;
  float4 b = *(const float4*)(p + 4);
  short8 r;
  r[0] = (short)f2bf(a.x); r[1] = (short)f2bf(a.y);
  r[2] = (short)f2bf(a.z); r[3] = (short)f2bf(a.w);
  r[4] = (short)f2bf(b.x); r[5] = (short)f2bf(b.y);
  r[6] = (short)f2bf(b.z); r[7] = (short)f2bf(b.w);
  return r;
}

// ---------------------------------------------------------------------------
// Async-stage ITERS*16 rows x 32 bf16 -> LDS [row][32], T2-swizzled.
// LDS dest is linear (global_load_lds HW requirement: base + lane*16B);
// the 16B k-slot is permuted on the GLOBAL side instead (rule #21):
//   physical slot (lane&3) holds logical k-chunk (lane&3)^((row>>1)&3),
//   with (row>>1)&3 == (lane>>3)&3 here since r0 % 16 == 0.
// Reader applies the same involution -> 2-way (free) bank access.
// Same 64B global segments as unswizzled -> coalescing unchanged.
// ---------------------------------------------------------------------------
template<int ITERS>
__device__ __forceinline__ void stage_async(const bf16raw* __restrict__ src, long ld,
                                            long row0, int k0, bf16raw* lds,
                                            int wave, int lane){
  int kchunk = (lane & 3) ^ ((lane >> 3) & 3);
#pragma unroll
  for (int i = 0; i < ITERS; ++i){
    int r0 = (wave*ITERS + i) * 16;
    long row = row0 + r0 + (lane >> 2);
    const bf16raw* gp = src + row*ld + k0 + kchunk*8;
    bf16raw* lp = lds + r0*32;
    __builtin_amdgcn_global_load_lds((const __attribute__((address_space(1))) void*)gp,
                                     (__attribute__((address_space(3))) void*)lp,
                                     16, 0, 0);
  }
}

// One BK=32 step: 4 A-frags + NI B-frags (ds_read_b128, swizzled slot) + 4*NI MFMA.
template<int NI>
__device__ __forceinline__ void mma_tile(const bf16raw* Alds, const bf16raw* Blds,
                                         f32x4 acc[4][NI], int wm, int wn, int quad, int t16){
  short8 af[4], bfr[NI];
  int sw = (quad ^ ((t16 >> 1) & 3)) * 8;   // physical 16B slot for this lane's rows
#pragma unroll
  for (int mi = 0; mi < 4; ++mi)
    af[mi] = *(const short8*)(Alds + (wm*64 + mi*16 + t16)*32 + sw);
#pragma unroll
  for (int ni = 0; ni < NI; ++ni)
    bfr[ni] = *(const short8*)(Blds + (wn*(NI*16) + ni*16 + t16)*32 + sw);
#pragma unroll
  for (int mi = 0; mi < 4; ++mi)
#pragma unroll
    for (int ni = 0; ni < NI; ++ni)
      acc[mi][ni] = __builtin_amdgcn_mfma_f32_16x16x32_bf16(af[mi], bfr[ni], acc[mi][ni], 0, 0, 0);
}

// ---------------------------------------------------------------------------
// Prep: fp32 -> bf16 for u, [W_omega|W_zeta|W_B] (concat), C, D_mat.
// ---------------------------------------------------------------------------
extern "C" __global__ void k_prep(const float* __restrict__ u,
    const float* __restrict__ Wom, const float* __restrict__ Wze,
    const float* __restrict__ WB, const float* __restrict__ Cm,
    const float* __restrict__ Dm, bf16raw* __restrict__ u_bf,
    bf16raw* __restrict__ Wcat, bf16raw* __restrict__ C_bf,
    bf16raw* __restrict__ Dm_bf){
  long g = (long)blockIdx.x * 256 + threadIdx.x;
  const float* src; bf16raw* dst; long o;
  if      (g < 2097152){ src = u;   dst = u_bf;          o = g; }
  else if (g < 2105344){ src = Wom; dst = Wcat;          o = g - 2097152; }
  else if (g < 2113536){ src = Wze; dst = Wcat + 65536;  o = g - 2105344; }
  else if (g < 2129920){ src = WB;  dst = Wcat + 131072; o = g - 2113536; }
  else if (g < 2146304){ src = Cm;  dst = C_bf;          o = g - 2129920; }
  else                 { src = Dm;  dst = Dm_bf;         o = g - 2146304; }
  *(short8*)(dst + o*8) = ld8f(src + o*8);
}

// ---------------------------------------------------------------------------
// K1: P[bt][n] = sum_d u[bt][d] * Wcat[n][d]  (16384 x 256, K=1024), fp32 out.
// Depth-2 prefetch, counted vmcnt(4) (4 global_load_lds per wave per stage),
// raw s_barrier (no vmcnt(0) drain), XCD-swizzled grid.
// ---------------------------------------------------------------------------
extern "C" __global__ __launch_bounds__(256) void k_gemm_p(
    const bf16raw* __restrict__ u_bf, const bf16raw* __restrict__ Wcat,
    float* __restrict__ P){
  __shared__ __align__(16) bf16raw Alds[2][128*32];
  __shared__ __align__(16) bf16raw Blds[2][128*32];
  int tid = threadIdx.x, wave = tid >> 6, lane = tid & 63;
  int quad = lane >> 4, t16 = lane & 15;
  int wm = wave >> 1, wn = wave & 1;
  // XCD-aware swizzle: 256 blocks, 8 XCDs x 32 consecutive blocks each.
  int id  = blockIdx.y * gridDim.x + blockIdx.x;
  int sid = (id & 7) * 32 + (id >> 3);
  long row0 = (long)(sid >> 1) * 128;
  int  col0 = (sid & 1) * 128;
  f32x4 acc[4][4] = {};

  auto stage = [&](int kt, int buf){
    stage_async<2>(u_bf, 1024, row0, kt*32, Alds[buf], wave, lane);
    stage_async<2>(Wcat, 1024, col0, kt*32, Blds[buf], wave, lane);
  };

  stage(0, 0);
  stage(1, 1);
  for (int kt = 0; kt < 30; ++kt){
    asm volatile("s_waitcnt vmcnt(4)" ::: "memory");  // oldest stage landed
    __builtin_amdgcn_s_barrier();
    __builtin_amdgcn_sched_barrier(0);
    __builtin_amdgcn_s_setprio(1);
    mma_tile<4>(Alds[kt & 1], Blds[kt & 1], acc, wm, wn, quad, t16);
    __builtin_amdgcn_s_setprio(0);
    __builtin_amdgcn_sched_barrier(0);
    __builtin_amdgcn_s_barrier();                     // all readers done
    stage(kt + 2, kt & 1);                            // overwrite, 2 ahead
  }
  asm volatile("s_waitcnt vmcnt(4)" ::: "memory");    // kt=30
  __builtin_amdgcn_s_barrier();
  __builtin_amdgcn_sched_barrier(0);
  mma_tile<4>(Alds[0], Blds[0], acc, wm, wn, quad, t16);
  asm volatile("s_waitcnt vmcnt(0)" ::: "memory");    // kt=31
  __builtin_amdgcn_s_barrier();
  __builtin_amdgcn_sched_barrier(0);
  mma_tile<4>(Alds[1], Blds[1], acc, wm, wn, quad, t16);
#pragma unroll
  for (int mi = 0; mi < 4; ++mi)
#pragma unroll
    for (int ni = 0; ni < 4; ++ni)
#pragma unroll
      for (int r = 0; r < 4; ++r){
        long grow = row0 + wm*64 + mi*16 + quad*4 + r;
        int  gcol = col0 + wn*64 + ni*16 + t16;
        P[grow*256 + gcol] = acc[mi][ni][r];
      }
}

// ---------------------------------------------------------------------------
// K4: out[bt][d] = sum_n Xs[bt][n]*C[d][n] + sum_e u[bt][e]*Dm[d][e], fp32 out.
// Unified 36-step K-loop (4 steps Xs@C^T + 32 steps u@Dm^T).
// Depth-2 prefetch, counted vmcnt(6) (6 loads/wave/stage), raw s_barrier,
// XCD-swizzled grid (4 col-tiles of a row-panel share one XCD's L2).
// ---------------------------------------------------------------------------
extern "C" __global__ __launch_bounds__(256, 2) void k_gemm_out(
    const bf16raw* __restrict__ Xs, const bf16raw* __restrict__ u_bf,
    const bf16raw* __restrict__ C_bf, const bf16raw* __restrict__ Dm_bf,
    float* __restrict__ out){
  __shared__ __align__(16) bf16raw Alds[2][128*32];
  __shared__ __align__(16) bf16raw Blds[2][256*32];
  int tid = threadIdx.x, wave = tid >> 6, lane = tid & 63;
  int quad = lane >> 4, t16 = lane & 15;
  int wm = wave >> 1, wn = wave & 1;
  // XCD-aware swizzle: 512 blocks, 8 XCDs x 64 consecutive blocks each.
  int id  = blockIdx.y * gridDim.x + blockIdx.x;
  int sid = (id & 7) * 64 + (id >> 3);
  long row0 = (long)(sid >> 2) * 128;
  int  col0 = (sid & 3) * 256;
  f32x4 acc[4][8] = {};

  auto stage = [&](int s, int buf){
    if (s < 4){
      stage_async<2>(Xs,   128, row0, s*32, Alds[buf], wave, lane);
      stage_async<4>(C_bf, 128, col0, s*32, Blds[buf], wave, lane);
    } else {
      stage_async<2>(u_bf,  1024, row0, (s-4)*32, Alds[buf], wave, lane);
      stage_async<4>(Dm_bf, 1024, col0, (s-4)*32, Blds[buf], wave, lane);
    }
  };

  stage(0, 0);
  stage(1, 1);
  for (int s = 0; s < 34; ++s){
    asm volatile("s_waitcnt vmcnt(6)" ::: "memory");  // oldest stage landed
    __builtin_amdgcn_s_barrier();
    __builtin_amdgcn_sched_barrier(0);
    __builtin_amdgcn_s_setprio(1);
    mma_tile<8>(Alds[s & 1], Blds[s & 1], acc, wm, wn, quad, t16);
    __builtin_amdgcn_s_setprio(0);
    __builtin_amdgcn_sched_barrier(0);
    __builtin_amdgcn_s_barrier();                     // all readers done
    stage(s + 2, s & 1);                              // overwrite, 2 ahead
  }
  asm volatile("s_waitcnt vmcnt(6)" ::: "memory");    // s=34
  __builtin_amdgcn_s_barrier();
  __builtin_amdgcn_sched_barrier(0);
  mma_tile<8>(Alds[0], Blds[0], acc, wm, wn, quad, t16);
  asm volatile("s_waitcnt vmcnt(0)" ::: "memory");    // s=35
  __builtin_amdgcn_s_barrier();
  __builtin_amdgcn_sched_barrier(0);
  mma_tile<8>(Alds[1], Blds[1], acc, wm, wn, quad, t16);
#pragma unroll
  for (int mi = 0; mi < 4; ++mi)
#pragma unroll
    for (int ni = 0; ni < 8; ++ni)
#pragma unroll
      for (int r = 0; r < 4; ++r){
        long grow = row0 + wm*64 + mi*16 + quad*4 + r;
        int  gcol = col0 + wn*128 + ni*16 + t16;
        out[grow*1024 + gcol] = acc[mi][ni][r];
      }
}

// ---------------------------------------------------------------------------
// scanA: fused coef + chunk summary. 256 chunks x 16 steps; block = chunk;
// thread tid = (b,m) series. Reads P once, writes Coef + per-chunk 2x2
// transition matrix CM and offset vector CV.
// ---------------------------------------------------------------------------
extern "C" __global__ __launch_bounds__(256) void k_scanA(
    const float* __restrict__ P, const float* __restrict__ b_om,
    const float* __restrict__ b_ze, const float* __restrict__ b_B,
    float4* __restrict__ Coef, float4* __restrict__ CM, float2* __restrict__ CV){
  int tid = threadIdx.x, c = blockIdx.x;
  int b = tid >> 6, m = tid & 63;
  float bo = b_om[m], bz = b_ze[m], bb0 = b_B[m], bb1 = b_B[64 + m];
  const float* row = P + ((size_t)b*4096 + c*16) * 256;
  float4* cf = Coef + ((size_t)b*4096 + c*16) * 64 + m;
  float m00=1.f, m01=0.f, m10=0.f, m11=0.f, vz=0.f, vy=0.f;
#pragma unroll 4
  for (int t = 0; t < 16; ++t){
    const float* r = row + t*256;
    float wo = r[m]       + bo;
    float wz = r[64 + m]  + bz;
    float fz = r[128 + m] + bb0;
    float fy = r[192 + m] + bb1;
    float sp = (wo > 20.f) ? wo : log1pf(expf(wo));
    float omega = fminf(fmaxf(sp, 1e-4f), 100.f);
    float A = omega * omega;
    float S = 1.f / (1.f + DTC*DTC*A);
    float zeta = 1.f / (1.f + expf(-wz));
    float p = (1.f - zeta) * S;
    float q = p * DTC * A;
    cf[t*64] = make_float4(p, q, fz, fy);
    float nvz = p*vz - q*vy + fz;
    float nvy = DTC*p*vz + p*vy + fy;
    vz = nvz; vy = nvy;
    float n00 = p*m00 - q*m10;
    float n01 = p*m01 - q*m11;
    float n10 = DTC*p*m00 + p*m10;
    float n11 = DTC*p*m01 + p*m11;
    m00=n00; m01=n01; m10=n10; m11=n11;
  }
  CM[c*256 + tid] = make_float4(m00, m01, m10, m11);
  CV[c*256 + tid] = make_float2(vz, vy);
}

// ---------------------------------------------------------------------------
// scanC: block c composes its own exclusive chunk prefix from CM/CV
// (parallel across blocks), then applies its chunk from Coef, writing Xs
// (bf16). Xs overlays P — safe: P fully consumed by k_scanA.
// ---------------------------------------------------------------------------
extern "C" __global__ __launch_bounds__(256) void k_scanC(
    const float4* __restrict__ Coef, const float4* __restrict__ CM,
    const float2* __restrict__ CV, bf16raw* __restrict__ Xs){
  int tid = threadIdx.x, c = blockIdx.x;
  int b = tid >> 6, m = tid & 63;
  float xz = 0.f, xy = 0.f;
#pragma unroll 4
  for (int j = 0; j < c; ++j){
    float4 Mv = CM[j*256 + tid];
    float2 Vv = CV[j*256 + tid];
    float nz = Mv.x*xz + Mv.y*xy + Vv.x;
    float ny = Mv.z*xz + Mv.w*xy + Vv.y;
    xz = nz; xy = ny;
  }
  const float4* cf = Coef + ((size_t)b*4096 + c*16) * 64 + m;
  bf16raw* xp = Xs + ((size_t)b*4096 + c*16) * 128 + m;
#pragma unroll 4
  for (int t = 0; t < 16; ++t){
    float4 f = cf[t*64];
    float nz = f.x*xz - f.y*xy + f.z;
    float ny = DTC*f.x*xz + f.x*xy + f.w;
    xz = nz; xy = ny;
    xp[t*128]      = f2bf(xz);   // z part: n = m
    xp[t*128 + 64] = f2bf(xy);   // y part: n = 64 + m
  }
}

// ---------------------------------------------------------------------------
extern "C" void kernel_launch(void* const* d_in, const int* in_sizes, int n_in,
                              void* d_out, int out_size, void* d_ws, size_t ws_size,
                              hipStream_t stream){
  const float* u   = (const float*)d_in[0];
  const float* Wom = (const float*)d_in[1];
  const float* bom = (const float*)d_in[2];
  const float* Wze = (const float*)d_in[3];
  const float* bze = (const float*)d_in[4];
  const float* WB  = (const float*)d_in[5];
  const float* bB  = (const float*)d_in[6];
  const float* Cm  = (const float*)d_in[7];
  const float* Dm  = (const float*)d_in[8];
  float* out = (float*)d_out;

  char* ws = (char*)d_ws;
  size_t off = 0;
  bf16raw* u_bf  = (bf16raw*)(ws + off); off += (size_t)16777216*2;    // 32 MB
  bf16raw* Wcat  = (bf16raw*)(ws + off); off += (size_t)262144*2;      // 512 KB
  bf16raw* C_bf  = (bf16raw*)(ws + off); off += (size_t)131072*2;      // 256 KB
  bf16raw* Dm_bf = (bf16raw*)(ws + off); off += (size_t)1048576*2;     // 2 MB
  float*   P     = (float*)  (ws + off);
  bf16raw* Xs    = (bf16raw*)P;          // overlay: P dead after k_scanA
  off += (size_t)16384*256*4;                                          // 16 MB
  float4*  Coef  = (float4*) (ws + off); off += (size_t)16384*64*16;   // 16 MB
  float4*  CMw   = (float4*) (ws + off); off += (size_t)256*256*16;    // 1 MB
  float2*  CVw   = (float2*) (ws + off); off += (size_t)256*256*8;     // 512 KB

  k_prep    <<<8896, 256, 0, stream>>>(u, Wom, Wze, WB, Cm, Dm, u_bf, Wcat, C_bf, Dm_bf);
  k_gemm_p  <<<dim3(2, 128), 256, 0, stream>>>(u_bf, Wcat, P);
  k_scanA   <<<256, 256, 0, stream>>>(P, bom, bze, bB, Coef, CMw, CVw);
  k_scanC   <<<256, 256, 0, stream>>>(Coef, CMw, CVw, Xs);
  k_gemm_out<<<dim3(4, 128), 256, 0, stream>>>(Xs, u_bf, C_bf, Dm_bf, out);
}

// Round 4
// 231.534 us; speedup vs baseline: 1.0388x; 1.0215x over previous
//
#include <hip/hip_runtime.h>
#include <hip/hip_bf16.h>
#include <math.h>

#define DTC 0.01f

typedef __attribute__((ext_vector_type(8))) short short8;   // 8 x bf16 (4 VGPRs)
typedef __attribute__((ext_vector_type(4))) float f32x4;    // MFMA C/D
typedef unsigned short bf16raw;

__device__ __forceinline__ bf16raw f2bf(float f){
  union { unsigned u; float f; } v; v.f = f;
  unsigned r = v.u + 0x7FFF + ((v.u >> 16) & 1u);   // round-to-nearest-even
  return (bf16raw)(r >> 16);
}

// Load 8 consecutive fp32, round to 8 bf16.
__device__ __forceinline__ short8 ld8f(const float* __restrict__ p){
  float4 a = *(const float4*)p;
  float4 b = *(const float4*)(p + 4);
  short8 r;
  r[0] = (short)f2bf(a.x); r[1] = (short)f2bf(a.y);
  r[2] = (short)f2bf(a.z); r[3] = (short)f2bf(a.w);
  r[4] = (short)f2bf(b.x); r[5] = (short)f2bf(b.y);
  r[6] = (short)f2bf(b.z); r[7] = (short)f2bf(b.w);
  return r;
}

// ---------------------------------------------------------------------------
// Async-stage ITERS*16 rows x 32 bf16 -> LDS [row][32], T2-swizzled.
// LDS dest linear (global_load_lds HW requirement); 16B k-slot permuted on
// the GLOBAL side (rule #21): slot (lane&3) holds k-chunk (lane&3)^((lane>>3)&3).
// Reader applies the same involution -> 2-way (free) bank access.
// ---------------------------------------------------------------------------
template<int ITERS>
__device__ __forceinline__ void stage_async(const bf16raw* __restrict__ src, long ld,
                                            long row0, int k0, bf16raw* lds,
                                            int wave, int lane){
  int kchunk = (lane & 3) ^ ((lane >> 3) & 3);
#pragma unroll
  for (int i = 0; i < ITERS; ++i){
    int r0 = (wave*ITERS + i) * 16;
    long row = row0 + r0 + (lane >> 2);
    const bf16raw* gp = src + row*ld + k0 + kchunk*8;
    bf16raw* lp = lds + r0*32;
    __builtin_amdgcn_global_load_lds((const __attribute__((address_space(1))) void*)gp,
                                     (__attribute__((address_space(3))) void*)lp,
                                     16, 0, 0);
  }
}

// One BK=32 step: MI A-frags + NI B-frags (ds_read_b128, swizzled slot) + MI*NI MFMA.
template<int MI, int NI>
__device__ __forceinline__ void mma_tile(const bf16raw* Alds, const bf16raw* Blds,
                                         f32x4 acc[MI][NI], int wm, int wn, int quad, int t16){
  short8 af[MI], bfr[NI];
  int sw = (quad ^ ((t16 >> 1) & 3)) * 8;   // physical 16B slot for this lane's rows
#pragma unroll
  for (int mi = 0; mi < MI; ++mi)
    af[mi] = *(const short8*)(Alds + (wm*(MI*16) + mi*16 + t16)*32 + sw);
#pragma unroll
  for (int ni = 0; ni < NI; ++ni)
    bfr[ni] = *(const short8*)(Blds + (wn*(NI*16) + ni*16 + t16)*32 + sw);
#pragma unroll
  for (int mi = 0; mi < MI; ++mi)
#pragma unroll
    for (int ni = 0; ni < NI; ++ni)
      acc[mi][ni] = __builtin_amdgcn_mfma_f32_16x16x32_bf16(af[mi], bfr[ni], acc[mi][ni], 0, 0, 0);
}

// ---------------------------------------------------------------------------
// Prep: fp32 -> bf16 for u, [W_omega|W_zeta|W_B] (concat), C, D_mat.
// ---------------------------------------------------------------------------
extern "C" __global__ void k_prep(const float* __restrict__ u,
    const float* __restrict__ Wom, const float* __restrict__ Wze,
    const float* __restrict__ WB, const float* __restrict__ Cm,
    const float* __restrict__ Dm, bf16raw* __restrict__ u_bf,
    bf16raw* __restrict__ Wcat, bf16raw* __restrict__ C_bf,
    bf16raw* __restrict__ Dm_bf){
  long g = (long)blockIdx.x * 256 + threadIdx.x;
  const float* src; bf16raw* dst; long o;
  if      (g < 2097152){ src = u;   dst = u_bf;          o = g; }
  else if (g < 2105344){ src = Wom; dst = Wcat;          o = g - 2097152; }
  else if (g < 2113536){ src = Wze; dst = Wcat + 65536;  o = g - 2105344; }
  else if (g < 2129920){ src = WB;  dst = Wcat + 131072; o = g - 2113536; }
  else if (g < 2146304){ src = Cm;  dst = C_bf;          o = g - 2129920; }
  else                 { src = Dm;  dst = Dm_bf;         o = g - 2146304; }
  *(short8*)(dst + o*8) = ld8f(src + o*8);
}

// ---------------------------------------------------------------------------
// K1: P[bt][n] = sum_d u[bt][d] * Wcat[n][d]  (16384 x 256, K=1024), fp32 out.
// Tile 64x128, 512 blocks (2/CU). Single-barrier 3-buffer pipeline:
// per step: vmcnt(3) -> s_barrier -> issue stage(s+2) -> MFMA(buf s%3).
// 3 loads/wave/stage (A<1> + B<2>); 2 stages in flight -> vmcnt(3).
// ---------------------------------------------------------------------------
extern "C" __global__ __launch_bounds__(256) void k_gemm_p(
    const bf16raw* __restrict__ u_bf, const bf16raw* __restrict__ Wcat,
    float* __restrict__ P){
  __shared__ __align__(16) bf16raw Alds[3*64*32];    // 12 KB
  __shared__ __align__(16) bf16raw Blds[3*128*32];   // 24 KB
  int tid = threadIdx.x, wave = tid >> 6, lane = tid & 63;
  int quad = lane >> 4, t16 = lane & 15;
  int wm = wave >> 1, wn = wave & 1;                 // wave tile 32x64
  // XCD-aware swizzle: 512 blocks, 8 XCDs x 64 consecutive blocks each.
  int id  = blockIdx.y * gridDim.x + blockIdx.x;
  int sid = (id & 7) * 64 + (id >> 3);
  long row0 = (long)(sid >> 1) * 64;
  int  col0 = (sid & 1) * 128;
  f32x4 acc[2][4] = {};

  auto stage = [&](int kt, int buf){
    stage_async<1>(u_bf, 1024, row0, kt*32, Alds + buf*(64*32), wave, lane);
    stage_async<2>(Wcat, 1024, col0, kt*32, Blds + buf*(128*32), wave, lane);
  };

  stage(0, 0);
  stage(1, 1);
  int rd = 0;                                        // rd = s % 3
  for (int s = 0; s < 30; ++s){
    asm volatile("s_waitcnt vmcnt(3)" ::: "memory"); // own stage-s loads landed
    __builtin_amdgcn_s_barrier();                    // => ALL waves' stage-s landed;
    __builtin_amdgcn_sched_barrier(0);               //    buf (s-1)%3 fully consumed
    int st = rd >= 1 ? rd - 1 : 2;                   // (s+2)%3 == (s-1)%3
    stage(s + 2, st);                                // issue early, before MFMA
    __builtin_amdgcn_s_setprio(1);
    mma_tile<2,4>(Alds + rd*(64*32), Blds + rd*(128*32), acc, wm, wn, quad, t16);
    __builtin_amdgcn_s_setprio(0);
    rd = rd < 2 ? rd + 1 : 0;
  }
  asm volatile("s_waitcnt vmcnt(3)" ::: "memory");   // s=30 reads buf 0
  __builtin_amdgcn_s_barrier();
  __builtin_amdgcn_sched_barrier(0);
  mma_tile<2,4>(Alds + 0*(64*32), Blds + 0*(128*32), acc, wm, wn, quad, t16);
  asm volatile("s_waitcnt vmcnt(0)" ::: "memory");   // s=31 reads buf 1
  __builtin_amdgcn_s_barrier();
  __builtin_amdgcn_sched_barrier(0);
  mma_tile<2,4>(Alds + 1*(64*32), Blds + 1*(128*32), acc, wm, wn, quad, t16);
#pragma unroll
  for (int mi = 0; mi < 2; ++mi)
#pragma unroll
    for (int ni = 0; ni < 4; ++ni)
#pragma unroll
      for (int r = 0; r < 4; ++r){
        long grow = row0 + wm*32 + mi*16 + quad*4 + r;
        int  gcol = col0 + wn*64 + ni*16 + t16;
        P[grow*256 + gcol] = acc[mi][ni][r];
      }
}

// ---------------------------------------------------------------------------
// K4: out[bt][d] = sum_n Xs[bt][n]*C[d][n] + sum_e u[bt][e]*Dm[d][e], fp32 out.
// Unified 36-step K-loop (4 steps Xs@C^T + 32 steps u@Dm^T).
// Single-barrier 3-buffer pipeline; 6 loads/wave/stage -> vmcnt(6).
// LDS 72 KB -> 2 blocks/CU. XCD-swizzled grid.
// ---------------------------------------------------------------------------
extern "C" __global__ __launch_bounds__(256, 2) void k_gemm_out(
    const bf16raw* __restrict__ Xs, const bf16raw* __restrict__ u_bf,
    const bf16raw* __restrict__ C_bf, const bf16raw* __restrict__ Dm_bf,
    float* __restrict__ out){
  __shared__ __align__(16) bf16raw Alds[3*128*32];   // 24 KB
  __shared__ __align__(16) bf16raw Blds[3*256*32];   // 48 KB
  int tid = threadIdx.x, wave = tid >> 6, lane = tid & 63;
  int quad = lane >> 4, t16 = lane & 15;
  int wm = wave >> 1, wn = wave & 1;                 // wave tile 64x128
  // XCD-aware swizzle: 512 blocks, 8 XCDs x 64 consecutive blocks each.
  int id  = blockIdx.y * gridDim.x + blockIdx.x;
  int sid = (id & 7) * 64 + (id >> 3);
  long row0 = (long)(sid >> 2) * 128;
  int  col0 = (sid & 3) * 256;
  f32x4 acc[4][8] = {};

  auto stage = [&](int s, int buf){
    if (s < 4){
      stage_async<2>(Xs,   128, row0, s*32, Alds + buf*(128*32), wave, lane);
      stage_async<4>(C_bf, 128, col0, s*32, Blds + buf*(256*32), wave, lane);
    } else {
      stage_async<2>(u_bf,  1024, row0, (s-4)*32, Alds + buf*(128*32), wave, lane);
      stage_async<4>(Dm_bf, 1024, col0, (s-4)*32, Blds + buf*(256*32), wave, lane);
    }
  };

  stage(0, 0);
  stage(1, 1);
  int rd = 0;                                        // rd = s % 3
  for (int s = 0; s < 34; ++s){
    asm volatile("s_waitcnt vmcnt(6)" ::: "memory"); // own stage-s loads landed
    __builtin_amdgcn_s_barrier();                    // all waves' stage-s landed;
    __builtin_amdgcn_sched_barrier(0);               // buf (s-1)%3 fully consumed
    int st = rd >= 1 ? rd - 1 : 2;                   // (s+2)%3
    stage(s + 2, st);                                // issue early, before MFMA
    __builtin_amdgcn_s_setprio(1);
    mma_tile<4,8>(Alds + rd*(128*32), Blds + rd*(256*32), acc, wm, wn, quad, t16);
    __builtin_amdgcn_s_setprio(0);
    rd = rd < 2 ? rd + 1 : 0;
  }
  asm volatile("s_waitcnt vmcnt(6)" ::: "memory");   // s=34 reads buf 1
  __builtin_amdgcn_s_barrier();
  __builtin_amdgcn_sched_barrier(0);
  mma_tile<4,8>(Alds + 1*(128*32), Blds + 1*(256*32), acc, wm, wn, quad, t16);
  asm volatile("s_waitcnt vmcnt(0)" ::: "memory");   // s=35 reads buf 2
  __builtin_amdgcn_s_barrier();
  __builtin_amdgcn_sched_barrier(0);
  mma_tile<4,8>(Alds + 2*(128*32), Blds + 2*(256*32), acc, wm, wn, quad, t16);
#pragma unroll
  for (int mi = 0; mi < 4; ++mi)
#pragma unroll
    for (int ni = 0; ni < 8; ++ni)
#pragma unroll
      for (int r = 0; r < 4; ++r){
        long grow = row0 + wm*64 + mi*16 + quad*4 + r;
        int  gcol = col0 + wn*128 + ni*16 + t16;
        out[grow*1024 + gcol] = acc[mi][ni][r];
      }
}

// ---------------------------------------------------------------------------
// scanA: fused coef + chunk summary. 256 chunks x 16 steps; block = chunk;
// thread tid = (b,m) series. Reads P once, writes Coef + per-chunk 2x2
// transition matrix CM and offset vector CV.
// ---------------------------------------------------------------------------
extern "C" __global__ __launch_bounds__(256) void k_scanA(
    const float* __restrict__ P, const float* __restrict__ b_om,
    const float* __restrict__ b_ze, const float* __restrict__ b_B,
    float4* __restrict__ Coef, float4* __restrict__ CM, float2* __restrict__ CV){
  int tid = threadIdx.x, c = blockIdx.x;
  int b = tid >> 6, m = tid & 63;
  float bo = b_om[m], bz = b_ze[m], bb0 = b_B[m], bb1 = b_B[64 + m];
  const float* row = P + ((size_t)b*4096 + c*16) * 256;
  float4* cf = Coef + ((size_t)b*4096 + c*16) * 64 + m;
  float m00=1.f, m01=0.f, m10=0.f, m11=0.f, vz=0.f, vy=0.f;
#pragma unroll 4
  for (int t = 0; t < 16; ++t){
    const float* r = row + t*256;
    float wo = r[m]       + bo;
    float wz = r[64 + m]  + bz;
    float fz = r[128 + m] + bb0;
    float fy = r[192 + m] + bb1;
    float sp = (wo > 20.f) ? wo : log1pf(expf(wo));
    float omega = fminf(fmaxf(sp, 1e-4f), 100.f);
    float A = omega * omega;
    float S = 1.f / (1.f + DTC*DTC*A);
    float zeta = 1.f / (1.f + expf(-wz));
    float p = (1.f - zeta) * S;
    float q = p * DTC * A;
    cf[t*64] = make_float4(p, q, fz, fy);
    float nvz = p*vz - q*vy + fz;
    float nvy = DTC*p*vz + p*vy + fy;
    vz = nvz; vy = nvy;
    float n00 = p*m00 - q*m10;
    float n01 = p*m01 - q*m11;
    float n10 = DTC*p*m00 + p*m10;
    float n11 = DTC*p*m01 + p*m11;
    m00=n00; m01=n01; m10=n10; m11=n11;
  }
  CM[c*256 + tid] = make_float4(m00, m01, m10, m11);
  CV[c*256 + tid] = make_float2(vz, vy);
}

// ---------------------------------------------------------------------------
// scanC: block c composes its own exclusive chunk prefix from CM/CV
// (parallel across blocks), then applies its chunk from Coef, writing Xs
// (bf16). Xs overlays P — safe: P fully consumed by k_scanA.
// ---------------------------------------------------------------------------
extern "C" __global__ __launch_bounds__(256) void k_scanC(
    const float4* __restrict__ Coef, const float4* __restrict__ CM,
    const float2* __restrict__ CV, bf16raw* __restrict__ Xs){
  int tid = threadIdx.x, c = blockIdx.x;
  int b = tid >> 6, m = tid & 63;
  float xz = 0.f, xy = 0.f;
#pragma unroll 4
  for (int j = 0; j < c; ++j){
    float4 Mv = CM[j*256 + tid];
    float2 Vv = CV[j*256 + tid];
    float nz = Mv.x*xz + Mv.y*xy + Vv.x;
    float ny = Mv.z*xz + Mv.w*xy + Vv.y;
    xz = nz; xy = ny;
  }
  const float4* cf = Coef + ((size_t)b*4096 + c*16) * 64 + m;
  bf16raw* xp = Xs + ((size_t)b*4096 + c*16) * 128 + m;
#pragma unroll 4
  for (int t = 0; t < 16; ++t){
    float4 f = cf[t*64];
    float nz = f.x*xz - f.y*xy + f.z;
    float ny = DTC*f.x*xz + f.x*xy + f.w;
    xz = nz; xy = ny;
    xp[t*128]      = f2bf(xz);   // z part: n = m
    xp[t*128 + 64] = f2bf(xy);   // y part: n = 64 + m
  }
}

// ---------------------------------------------------------------------------
extern "C" void kernel_launch(void* const* d_in, const int* in_sizes, int n_in,
                              void* d_out, int out_size, void* d_ws, size_t ws_size,
                              hipStream_t stream){
  const float* u   = (const float*)d_in[0];
  const float* Wom = (const float*)d_in[1];
  const float* bom = (const float*)d_in[2];
  const float* Wze = (const float*)d_in[3];
  const float* bze = (const float*)d_in[4];
  const float* WB  = (const float*)d_in[5];
  const float* bB  = (const float*)d_in[6];
  const float* Cm  = (const float*)d_in[7];
  const float* Dm  = (const float*)d_in[8];
  float* out = (float*)d_out;

  char* ws = (char*)d_ws;
  size_t off = 0;
  bf16raw* u_bf  = (bf16raw*)(ws + off); off += (size_t)16777216*2;    // 32 MB
  bf16raw* Wcat  = (bf16raw*)(ws + off); off += (size_t)262144*2;      // 512 KB
  bf16raw* C_bf  = (bf16raw*)(ws + off); off += (size_t)131072*2;      // 256 KB
  bf16raw* Dm_bf = (bf16raw*)(ws + off); off += (size_t)1048576*2;     // 2 MB
  float*   P     = (float*)  (ws + off);
  bf16raw* Xs    = (bf16raw*)P;          // overlay: P dead after k_scanA
  off += (size_t)16384*256*4;                                          // 16 MB
  float4*  Coef  = (float4*) (ws + off); off += (size_t)16384*64*16;   // 16 MB
  float4*  CMw   = (float4*) (ws + off); off += (size_t)256*256*16;    // 1 MB
  float2*  CVw   = (float2*) (ws + off); off += (size_t)256*256*8;     // 512 KB

  k_prep    <<<8896, 256, 0, stream>>>(u, Wom, Wze, WB, Cm, Dm, u_bf, Wcat, C_bf, Dm_bf);
  k_gemm_p  <<<dim3(2, 256), 256, 0, stream>>>(u_bf, Wcat, P);
  k_scanA   <<<256, 256, 0, stream>>>(P, bom, bze, bB, Coef, CMw, CVw);
  k_scanC   <<<256, 256, 0, stream>>>(Coef, CMw, CVw, Xs);
  k_gemm_out<<<dim3(4, 128), 256, 0, stream>>>(Xs, u_bf, C_bf, Dm_bf, out);
}